// Round 1
// baseline (522.846 us; speedup 1.0000x reference)
//
#include <hip/hip_runtime.h>
#include <cstdint>
#include <cstddef>

#define H_  16
#define V_  8
#define DH_ 128
#define B_  4096
#define BT  32      // batch rows per block
#define LDST 132    // padded LDS row stride (floats)

// ---------------------------------------------------------------------------
// Kernel A: precompute M[h] = Wq[h]^T @ Wk[h]   (layout M[h][d][d'])
//           and      NT[h] = (Wo[h] @ Wv[h])^T  (layout NT[h][d'][e])
// grid = 2*H*8 = 256 blocks, 256 threads. Each block: 16 rows x 128 cols.
// ---------------------------------------------------------------------------
__global__ __launch_bounds__(256) void precompute_MN(
    const float* __restrict__ Wq, const float* __restrict__ Wk,
    const float* __restrict__ Wv, const float* __restrict__ Wo,
    float* __restrict__ Mmat, float* __restrict__ NTmat)
{
    const int bx    = blockIdx.x;
    const int which = bx & 1;
    const int h     = (bx >> 1) & 15;
    const int chunk = bx >> 5;              // 0..7
    const int tid   = threadIdx.x;
    const int col   = tid & 127;
    const int r0    = chunk * 16 + (tid >> 7) * 8;

    float acc[8];
#pragma unroll
    for (int r = 0; r < 8; ++r) acc[r] = 0.f;

    if (which == 0) {
        // M[d][d'] = sum_e Wq[e][d] * Wk[e][d'];  row=d (r0+r), col=d'
        const float* wq = Wq + h * DH_ * DH_;
        const float* wk = Wk + h * DH_ * DH_;
        for (int e = 0; e < DH_; ++e) {
            const float bk = wk[e * DH_ + col];
#pragma unroll
            for (int r = 0; r < 8; ++r) acc[r] += wq[e * DH_ + r0 + r] * bk;
        }
        float* dst = Mmat + h * DH_ * DH_;
#pragma unroll
        for (int r = 0; r < 8; ++r) dst[(r0 + r) * DH_ + col] = acc[r];
    } else {
        // NT[d'][e] = sum_d Wo[e][d] * Wv[d][d'];  row=d' (r0+r), col=e
        const float* wo = Wo + h * DH_ * DH_;
        const float* wv = Wv + h * DH_ * DH_;
        for (int d = 0; d < DH_; ++d) {
            const float bo = wo[col * DH_ + d];
#pragma unroll
            for (int r = 0; r < 8; ++r) acc[r] += wv[d * DH_ + r0 + r] * bo;
        }
        float* dst = NTmat + h * DH_ * DH_;
#pragma unroll
        for (int r = 0; r < 8; ++r) dst[(r0 + r) * DH_ + col] = acc[r];
    }
}

// ---------------------------------------------------------------------------
// Kernel B: fused per-(b,h) pipeline.
//   qk  = iso @ M           (32x128 = 32x128 @ 128x128, reg-tiled 4x4)
//   s_v = qk . view[v] / sqrt(DH) + log(pi+eps); attn = softmax_v
//   ctx = sum_v attn[v] * view[v]
//   out = ctx @ NT          (reg-tiled 4x4)
// grid = H * (B/BT) = 2048 blocks, 256 threads (4 waves).
// ---------------------------------------------------------------------------
__global__ __launch_bounds__(256) void fused_attn(
    const float* __restrict__ iso, const float* __restrict__ view,
    const float* __restrict__ pi,
    const float* __restrict__ Mmat, const float* __restrict__ NTmat,
    float* __restrict__ out, float* __restrict__ attn_out)
{
    __shared__ float buf_s[BT][LDST];   // iso tile, later reused as ctx tile
    __shared__ float qk_s[BT][LDST];
    __shared__ float attn_s[BT][V_];

    const int tid = threadIdx.x;
    const int h   = blockIdx.x >> 7;           // 128 b-tiles per head
    const int b0  = (blockIdx.x & 127) * BT;

    // ---- stage iso tile: 32 rows x 128 floats, fully coalesced float4 loads
#pragma unroll
    for (int i = 0; i < 4; ++i) {
        const int idx = tid + i * 256;         // one float4 each, 1024 total
        const int b   = idx >> 5;              // 32 float4 per row
        const int dq  = idx & 31;
        const float4 v4 = *(const float4*)(iso + ((size_t)(b0 + b) * H_ + h) * DH_ + dq * 4);
        *(float4*)&buf_s[b][dq * 4] = v4;
    }
    __syncthreads();

    const int tx = tid & 31;                   // output-col quad (d' = tx*4..+3)
    const int ty = tid >> 5;                   // output-row group (b = ty*4..+3)

    // ---- phase 1: qk[b][d'] = sum_d iso[b][d] * M[d][d']
    {
        const float* Mh = Mmat + h * DH_ * DH_ + tx * 4;
        float acc[4][4];
#pragma unroll
        for (int i = 0; i < 4; ++i)
#pragma unroll
            for (int j = 0; j < 4; ++j) acc[i][j] = 0.f;

        for (int d = 0; d < DH_; d += 4) {
            const float4 m0 = *(const float4*)(Mh + (size_t)(d + 0) * DH_);
            const float4 m1 = *(const float4*)(Mh + (size_t)(d + 1) * DH_);
            const float4 m2 = *(const float4*)(Mh + (size_t)(d + 2) * DH_);
            const float4 m3 = *(const float4*)(Mh + (size_t)(d + 3) * DH_);
#pragma unroll
            for (int i = 0; i < 4; ++i) {
                const float4 a = *(const float4*)&buf_s[ty * 4 + i][d];
                acc[i][0] += a.x * m0.x + a.y * m1.x + a.z * m2.x + a.w * m3.x;
                acc[i][1] += a.x * m0.y + a.y * m1.y + a.z * m2.y + a.w * m3.y;
                acc[i][2] += a.x * m0.z + a.y * m1.z + a.z * m2.z + a.w * m3.z;
                acc[i][3] += a.x * m0.w + a.y * m1.w + a.z * m2.w + a.w * m3.w;
            }
        }
#pragma unroll
        for (int i = 0; i < 4; ++i)
            *(float4*)&qk_s[ty * 4 + i][tx * 4] =
                make_float4(acc[i][0], acc[i][1], acc[i][2], acc[i][3]);
    }
    __syncthreads();   // qk ready; iso tile dead (buf_s reusable)

    // ---- phase 2a: scores + softmax. one thread per (b, v): 32*8 = 256
    {
        const int bl = tid >> 3;
        const int v  = tid & 7;
        const float* vrow = view + (((size_t)(b0 + bl) * H_ + h) * V_ + v) * DH_;
        float s0 = 0.f, s1 = 0.f, s2 = 0.f, s3 = 0.f;
        for (int d = 0; d < DH_; d += 4) {
            const float4 w = *(const float4*)(vrow + d);
            const float4 q = *(const float4*)&qk_s[bl][d];
            s0 += w.x * q.x; s1 += w.y * q.y; s2 += w.z * q.z; s3 += w.w * q.w;
        }
        float sc = (s0 + s1) + (s2 + s3);
        sc *= 0.08838834764831845f;            // 1/sqrt(128)
        sc += logf(pi[((size_t)(b0 + bl) * H_ + h) * V_ + v] + 1e-6f);

        // softmax across the 8 v-lanes (contiguous within the wave)
        float mx = sc;
        mx = fmaxf(mx, __shfl_xor(mx, 1));
        mx = fmaxf(mx, __shfl_xor(mx, 2));
        mx = fmaxf(mx, __shfl_xor(mx, 4));
        const float ex = expf(sc - mx);
        float sm = ex;
        sm += __shfl_xor(sm, 1);
        sm += __shfl_xor(sm, 2);
        sm += __shfl_xor(sm, 4);
        const float at = ex / sm;
        attn_s[bl][v] = at;
        attn_out[((size_t)(b0 + bl) * H_ + h) * V_ + v] = at;   // coalesced
    }
    __syncthreads();   // attn ready

    // ---- phase 2b: ctx[b][d'] = sum_v attn[v]*view[b,h,v,d'] -> buf_s
    {
        const int bl2 = tid >> 3;
        const int dq  = tid & 7;               // d' block of 16
        float av[V_];
#pragma unroll
        for (int j = 0; j < V_; ++j) av[j] = attn_s[bl2][j];

        const float* vbase = view + (((size_t)(b0 + bl2) * H_ + h) * V_) * DH_ + dq * 16;
        float c[16];
#pragma unroll
        for (int j = 0; j < 16; ++j) c[j] = 0.f;
        for (int vv = 0; vv < V_; ++vv) {
            const float* p = vbase + (size_t)vv * DH_;
#pragma unroll
            for (int j4 = 0; j4 < 4; ++j4) {
                const float4 x = *(const float4*)(p + j4 * 4);
                c[j4 * 4 + 0] += av[vv] * x.x;
                c[j4 * 4 + 1] += av[vv] * x.y;
                c[j4 * 4 + 2] += av[vv] * x.z;
                c[j4 * 4 + 3] += av[vv] * x.w;
            }
        }
#pragma unroll
        for (int j4 = 0; j4 < 4; ++j4)
            *(float4*)&buf_s[bl2][dq * 16 + j4 * 4] =
                make_float4(c[j4 * 4 + 0], c[j4 * 4 + 1], c[j4 * 4 + 2], c[j4 * 4 + 3]);
    }
    __syncthreads();   // ctx ready

    // ---- phase 3: out[b][e] = sum_d' ctx[b][d'] * NT[d'][e]
    {
        const float* Nh = NTmat + h * DH_ * DH_ + tx * 4;
        float acc[4][4];
#pragma unroll
        for (int i = 0; i < 4; ++i)
#pragma unroll
            for (int j = 0; j < 4; ++j) acc[i][j] = 0.f;

        for (int dp = 0; dp < DH_; dp += 4) {
            const float4 n0 = *(const float4*)(Nh + (size_t)(dp + 0) * DH_);
            const float4 n1 = *(const float4*)(Nh + (size_t)(dp + 1) * DH_);
            const float4 n2 = *(const float4*)(Nh + (size_t)(dp + 2) * DH_);
            const float4 n3 = *(const float4*)(Nh + (size_t)(dp + 3) * DH_);
#pragma unroll
            for (int i = 0; i < 4; ++i) {
                const float4 a = *(const float4*)&buf_s[ty * 4 + i][dp];
                acc[i][0] += a.x * n0.x + a.y * n1.x + a.z * n2.x + a.w * n3.x;
                acc[i][1] += a.x * n0.y + a.y * n1.y + a.z * n2.y + a.w * n3.y;
                acc[i][2] += a.x * n0.z + a.y * n1.z + a.z * n2.z + a.w * n3.z;
                acc[i][3] += a.x * n0.w + a.y * n1.w + a.z * n2.w + a.w * n3.w;
            }
        }
#pragma unroll
        for (int i = 0; i < 4; ++i)
            *(float4*)(out + ((size_t)(b0 + ty * 4 + i) * H_ + h) * DH_ + tx * 4) =
                make_float4(acc[i][0], acc[i][1], acc[i][2], acc[i][3]);
    }
}

// ---------------------------------------------------------------------------
extern "C" void kernel_launch(void* const* d_in, const int* in_sizes, int n_in,
                              void* d_out, int out_size, void* d_ws, size_t ws_size,
                              hipStream_t stream)
{
    const float* iso  = (const float*)d_in[0];   // [B,H,DH]
    const float* view = (const float*)d_in[1];   // [B,H,V,DH]
    const float* pi   = (const float*)d_in[2];   // [B,H,V]
    const float* Wq   = (const float*)d_in[3];   // [H,DH,DH]
    const float* Wk   = (const float*)d_in[4];
    const float* Wv   = (const float*)d_in[5];
    const float* Wo   = (const float*)d_in[6];

    float* out  = (float*)d_out;                           // [B,H,DH]
    float* attn = out + (size_t)B_ * H_ * DH_;             // [B,H,V]

    float* Mmat  = (float*)d_ws;                           // H*DH*DH floats (1 MB)
    float* NTmat = Mmat + (size_t)H_ * DH_ * DH_;          // H*DH*DH floats (1 MB)

    hipLaunchKernelGGL(precompute_MN, dim3(256), dim3(256), 0, stream,
                       Wq, Wk, Wv, Wo, Mmat, NTmat);
    hipLaunchKernelGGL(fused_attn, dim3(H_ * (B_ / BT)), dim3(256), 0, stream,
                       iso, view, pi, Mmat, NTmat, out, attn);
}

// Round 2
// 518.014 us; speedup vs baseline: 1.0093x; 1.0093x over previous
//
#include <hip/hip_runtime.h>
#include <cstdint>
#include <cstddef>

#define H_  16
#define V_  8
#define DH_ 128
#define B_  4096
#define BT  32      // batch rows per block
#define LDST 132    // padded LDS row stride (floats)

// ---------------------------------------------------------------------------
// Kernel A: precompute M[h] = Wq[h]^T @ Wk[h]   (layout M[h][d][d'])
//           and      NT[h] = (Wo[h] @ Wv[h])^T  (layout NT[h][d'][e])
// grid = 2*H*8 = 256 blocks, 256 threads. Each block: 16 rows x 128 cols.
// All loads coalesced or wave-uniform (broadcast).
// ---------------------------------------------------------------------------
__global__ __launch_bounds__(256) void precompute_MN(
    const float* __restrict__ Wq, const float* __restrict__ Wk,
    const float* __restrict__ Wv, const float* __restrict__ Wo,
    float* __restrict__ Mmat, float* __restrict__ NTmat)
{
    const int bx    = blockIdx.x;
    const int which = bx & 1;
    const int h     = (bx >> 1) & 15;
    const int chunk = bx >> 5;              // 0..7
    const int tid   = threadIdx.x;
    const int col   = tid & 127;
    const int r0    = chunk * 16 + (tid >> 7) * 8;

    float acc[8];
#pragma unroll
    for (int r = 0; r < 8; ++r) acc[r] = 0.f;

    if (which == 0) {
        // M[d][d'] = sum_e Wq[e][d] * Wk[e][d'];  row=d (r0+r), col=d'
        const float* wq = Wq + h * DH_ * DH_;
        const float* wk = Wk + h * DH_ * DH_;
        for (int e = 0; e < DH_; ++e) {
            const float bk = wk[e * DH_ + col];        // coalesced
#pragma unroll
            for (int r = 0; r < 8; ++r) acc[r] += wq[e * DH_ + r0 + r] * bk;  // uniform
        }
        float* dst = Mmat + h * DH_ * DH_;
#pragma unroll
        for (int r = 0; r < 8; ++r) dst[(r0 + r) * DH_ + col] = acc[r];
    } else {
        // N2[e][d'] = sum_d Wo[e][d] * Wv[d][d'];  row=e (r0+r), col=d'
        // stored TRANSPOSED into NT[d'][e] so phase-3 streaming stays coalesced.
        const float* wo = Wo + h * DH_ * DH_;
        const float* wv = Wv + h * DH_ * DH_;
        for (int d = 0; d < DH_; ++d) {
            const float bv = wv[d * DH_ + col];        // coalesced
#pragma unroll
            for (int r = 0; r < 8; ++r) acc[r] += wo[(r0 + r) * DH_ + d] * bv; // uniform
        }
        float* dst = NTmat + h * DH_ * DH_;
#pragma unroll
        for (int r = 0; r < 8; ++r) dst[(size_t)col * DH_ + (r0 + r)] = acc[r]; // scattered store, tiny
    }
}

// ---------------------------------------------------------------------------
// Kernel B: fused per-(b,h) pipeline.
//   qk  = iso @ M           (32x128 = 32x128 @ 128x128, reg-tiled 4x4)
//   s_v = qk . view[v] / sqrt(DH) + log(pi+eps); attn = softmax_v
//   ctx = sum_v attn[v] * view[v]
//   out = ctx @ NT          (reg-tiled 4x4)
// grid = H * (B/BT) = 2048 blocks, 256 threads (4 waves).
// view is read with fully coalesced 512B-per-half-wave bursts.
// ---------------------------------------------------------------------------
__global__ __launch_bounds__(256) void fused_attn(
    const float* __restrict__ iso, const float* __restrict__ view,
    const float* __restrict__ pi,
    const float* __restrict__ Mmat, const float* __restrict__ NTmat,
    float* __restrict__ out, float* __restrict__ attn_out)
{
    __shared__ float buf_s[BT][LDST];   // iso tile, later reused as ctx tile
    __shared__ float qk_s[BT][LDST];
    __shared__ float sc_s[BT][V_];      // raw scores (dot only)
    __shared__ float attn_s[BT][V_];

    const int tid = threadIdx.x;
    const int h   = blockIdx.x >> 7;           // 128 b-tiles per head
    const int b0  = (blockIdx.x & 127) * BT;

    // ---- stage iso tile: 32 rows x 128 floats, fully coalesced float4 loads
#pragma unroll
    for (int i = 0; i < 4; ++i) {
        const int idx = tid + i * 256;         // one float4 each, 1024 total
        const int b   = idx >> 5;              // 32 float4 per row
        const int dq  = idx & 31;
        const float4 v4 = *(const float4*)(iso + ((size_t)(b0 + b) * H_ + h) * DH_ + dq * 4);
        *(float4*)&buf_s[b][dq * 4] = v4;
    }
    __syncthreads();

    const int tx = tid & 31;                   // output-col quad (d' = tx*4..+3)
    const int ty = tid >> 5;                   // output-row group (b = ty*4..+3)

    // ---- phase 1: qk[b][d'] = sum_d iso[b][d] * M[d][d']
    {
        const float* Mh = Mmat + h * DH_ * DH_ + tx * 4;
        float acc[4][4];
#pragma unroll
        for (int i = 0; i < 4; ++i)
#pragma unroll
            for (int j = 0; j < 4; ++j) acc[i][j] = 0.f;

        for (int d = 0; d < DH_; d += 4) {
            const float4 m0 = *(const float4*)(Mh + (size_t)(d + 0) * DH_);
            const float4 m1 = *(const float4*)(Mh + (size_t)(d + 1) * DH_);
            const float4 m2 = *(const float4*)(Mh + (size_t)(d + 2) * DH_);
            const float4 m3 = *(const float4*)(Mh + (size_t)(d + 3) * DH_);
#pragma unroll
            for (int i = 0; i < 4; ++i) {
                const float4 a = *(const float4*)&buf_s[ty * 4 + i][d];
                acc[i][0] += a.x * m0.x + a.y * m1.x + a.z * m2.x + a.w * m3.x;
                acc[i][1] += a.x * m0.y + a.y * m1.y + a.z * m2.y + a.w * m3.y;
                acc[i][2] += a.x * m0.z + a.y * m1.z + a.z * m2.z + a.w * m3.z;
                acc[i][3] += a.x * m0.w + a.y * m1.w + a.z * m2.w + a.w * m3.w;
            }
        }
#pragma unroll
        for (int i = 0; i < 4; ++i)
            *(float4*)&qk_s[ty * 4 + i][tx * 4] =
                make_float4(acc[i][0], acc[i][1], acc[i][2], acc[i][3]);
    }
    __syncthreads();   // qk ready; iso tile dead (buf_s reusable)

    // ---- phase 2a: scores. Half-wave (32 lanes) per view row, coalesced.
    // wave w handles pairs p = w*64 + it*2 + half, p -> (b = p>>3, v = p&7)
    {
        const int wv   = tid >> 6;             // wave id 0..3
        const int lane = tid & 63;
        const int half = lane >> 5;            // 0/1: which row of the pair
        const int l32  = lane & 31;            // d-chunk: floats l32*4..+3
#pragma unroll 4
        for (int it = 0; it < 32; ++it) {
            const int p  = wv * 64 + it * 2 + half;
            const int bl = p >> 3;
            const int v  = p & 7;
            const float4 w = *(const float4*)(view +
                (((size_t)(b0 + bl) * H_ + h) * V_ + v) * DH_ + l32 * 4);
            const float4 q = *(const float4*)&qk_s[bl][l32 * 4];
            float s = w.x * q.x + w.y * q.y + w.z * q.z + w.w * q.w;
            // reduce across the 32-lane half (xor masks stay within the half)
            s += __shfl_xor(s, 1);
            s += __shfl_xor(s, 2);
            s += __shfl_xor(s, 4);
            s += __shfl_xor(s, 8);
            s += __shfl_xor(s, 16);
            if (l32 == 0) sc_s[bl][v] = s;
        }
    }
    __syncthreads();   // raw scores ready

    // ---- phase 2a': softmax. one thread per (b, v): 32*8 = 256
    {
        const int bl = tid >> 3;
        const int v  = tid & 7;
        float sc = sc_s[bl][v] * 0.08838834764831845f;   // 1/sqrt(128)
        sc += logf(pi[((size_t)(b0 + bl) * H_ + h) * V_ + v] + 1e-6f);

        // softmax across the 8 v-lanes (contiguous within the wave)
        float mx = sc;
        mx = fmaxf(mx, __shfl_xor(mx, 1));
        mx = fmaxf(mx, __shfl_xor(mx, 2));
        mx = fmaxf(mx, __shfl_xor(mx, 4));
        const float ex = expf(sc - mx);
        float sm = ex;
        sm += __shfl_xor(sm, 1);
        sm += __shfl_xor(sm, 2);
        sm += __shfl_xor(sm, 4);
        const float at = ex / sm;
        attn_s[bl][v] = at;
        attn_out[((size_t)(b0 + bl) * H_ + h) * V_ + v] = at;
    }
    __syncthreads();   // attn ready

    // ---- phase 2b: ctx[b][d'] = sum_v attn[v]*view[b,h,v,d'] -> buf_s
    // 32 lanes per b-row, lane owns d' = l32*4..+3. view rows hit L1/L2.
    {
        const int bg  = tid >> 5;              // 0..7: row within group of 8
        const int l32 = tid & 31;
#pragma unroll
        for (int r = 0; r < 4; ++r) {
            const int b = r * 8 + bg;
            const float* vbase = view + (((size_t)(b0 + b) * H_ + h) * V_) * DH_ + l32 * 4;
            float4 c = make_float4(0.f, 0.f, 0.f, 0.f);
#pragma unroll
            for (int vv = 0; vv < V_; ++vv) {
                const float a = attn_s[b][vv];                 // LDS broadcast
                const float4 x = *(const float4*)(vbase + (size_t)vv * DH_);
                c.x += a * x.x; c.y += a * x.y; c.z += a * x.z; c.w += a * x.w;
            }
            *(float4*)&buf_s[b][l32 * 4] = c;
        }
    }
    __syncthreads();   // ctx ready

    // ---- phase 3: out[b][e] = sum_d' ctx[b][d'] * NT[d'][e]
    {
        const float* Nh = NTmat + h * DH_ * DH_ + tx * 4;
        float acc[4][4];
#pragma unroll
        for (int i = 0; i < 4; ++i)
#pragma unroll
            for (int j = 0; j < 4; ++j) acc[i][j] = 0.f;

        for (int dp = 0; dp < DH_; dp += 4) {
            const float4 n0 = *(const float4*)(Nh + (size_t)(dp + 0) * DH_);
            const float4 n1 = *(const float4*)(Nh + (size_t)(dp + 1) * DH_);
            const float4 n2 = *(const float4*)(Nh + (size_t)(dp + 2) * DH_);
            const float4 n3 = *(const float4*)(Nh + (size_t)(dp + 3) * DH_);
#pragma unroll
            for (int i = 0; i < 4; ++i) {
                const float4 a = *(const float4*)&buf_s[ty * 4 + i][dp];
                acc[i][0] += a.x * n0.x + a.y * n1.x + a.z * n2.x + a.w * n3.x;
                acc[i][1] += a.x * n0.y + a.y * n1.y + a.z * n2.y + a.w * n3.y;
                acc[i][2] += a.x * n0.z + a.y * n1.z + a.z * n2.z + a.w * n3.z;
                acc[i][3] += a.x * n0.w + a.y * n1.w + a.z * n2.w + a.w * n3.w;
            }
        }
#pragma unroll
        for (int i = 0; i < 4; ++i)
            *(float4*)(out + ((size_t)(b0 + ty * 4 + i) * H_ + h) * DH_ + tx * 4) =
                make_float4(acc[i][0], acc[i][1], acc[i][2], acc[i][3]);
    }
}

// ---------------------------------------------------------------------------
extern "C" void kernel_launch(void* const* d_in, const int* in_sizes, int n_in,
                              void* d_out, int out_size, void* d_ws, size_t ws_size,
                              hipStream_t stream)
{
    const float* iso  = (const float*)d_in[0];   // [B,H,DH]
    const float* view = (const float*)d_in[1];   // [B,H,V,DH]
    const float* pi   = (const float*)d_in[2];   // [B,H,V]
    const float* Wq   = (const float*)d_in[3];   // [H,DH,DH]
    const float* Wk   = (const float*)d_in[4];
    const float* Wv   = (const float*)d_in[5];
    const float* Wo   = (const float*)d_in[6];

    float* out  = (float*)d_out;                           // [B,H,DH]
    float* attn = out + (size_t)B_ * H_ * DH_;             // [B,H,V]

    float* Mmat  = (float*)d_ws;                           // H*DH*DH floats (1 MB)
    float* NTmat = Mmat + (size_t)H_ * DH_ * DH_;          // H*DH*DH floats (1 MB)

    hipLaunchKernelGGL(precompute_MN, dim3(256), dim3(256), 0, stream,
                       Wq, Wk, Wv, Wo, Mmat, NTmat);
    hipLaunchKernelGGL(fused_attn, dim3(H_ * (B_ / BT)), dim3(256), 0, stream,
                       iso, view, pi, Mmat, NTmat, out, attn);
}